// Round 10
// baseline (105.468 us; speedup 1.0000x reference)
//
#include <hip/hip_runtime.h>
#include <hip/hip_bf16.h>
#include <math.h>

// Chamfer distance, B=8, N=M=8192, D=3, fp32.
//   C[m][n] = q_m.r_n - 0.5*||r_n||^2 via ONE v_mfma_f32_32x32x16_bf16:
//     lanes<32  (k0-7) : A={qh,1, ql,0}  B={rh,wh, rh,wh}
//     lanes>=32 (k8-15): A={qh,1, 0,0}   B={rl,wl, 0,0}
//   min_j d2 = ||q||^2_fp32 - 2*max_n C, clamped at 0.
// R16: R15 failed numerics (absmax 3.4e-3) -> the inline-asm v_max3 reading
// MFMA-intrinsic dests is NOT padded by the MAI hazard recognizer (it does
// not model INLINEASM uses; mirror of R9's failure). LESSON: keep the whole
// MFMA->fold path in compiler-known instructions. This round isolates the
// R15 occupancy lever with the numerically-proven fmaxf fold (absmax 0.0 in
// R11/R12/R14; LLVM fuses maxnum(maxnum(a,b),c) -> v_max3_f32 on gfx9+):
//   - QPW=32: wave = one 32-query A-frag; 2 MFMA + 16 fold per 2 tiles
//     (fold VALU demand = 1/2 of MFMA demand, the floor)
//   - grid 64x16 = 1024 blocks = exactly 4/CU = 4 waves/SIMD
//     (launch_bounds(256,4), ~100 regs, 18KB LDS)
//   - S/T ping-pong register prefetch; wave-private epilogue; no barriers
// Predicted: chamfer 43.5 -> 20-28us (MfmaUtil 50-70), total ~70-78us.
// Pre-commit: chamfer 35-45us + MfmaUtil ~33 despite this => cross-wave
// overlap unattainable for this mix; ~40us is the kernel attractor.

#define BLOCK 256
#define WAVES 4
#define QPW 32        // queries per wave (one 32-row MFMA group)

typedef short short8 __attribute__((ext_vector_type(8)));
typedef float f32x16 __attribute__((ext_vector_type(16)));

__device__ __forceinline__ unsigned int bf16hi(float f) {
    __hip_bfloat16 h = __float2bfloat16(f);
    return (unsigned int)*reinterpret_cast<unsigned short*>(&h);
}
__device__ __forceinline__ float bf16f(unsigned int u) {
    unsigned int v = u << 16;
    return *reinterpret_cast<float*>(&v);
}
__device__ __forceinline__ void cvt_split(float v, unsigned int& hi, unsigned int& lo) {
    hi = bf16hi(v);
    lo = bf16hi(v - bf16f(hi));
}

#define MFMA(a, b, c) __builtin_amdgcn_mfma_f32_32x32x16_bf16((a), (b), (c), 0, 0, 0)

// recB: pre-expanded B-fragment stream, tile t = points [32t,32t+32),
// 1024B per tile:
//   bytes [t*1024 + m*16]       = {hx,hz, hx,hz}  (hi dup, consumed by lanes<32)
//   bytes [t*1024 + 512 + m*16] = {lx,lz, 0, 0}   (lo,     consumed by lanes>=32)
// where hx = xh|(yh<<16), hz = zh|(wh<<16), w = -0.5*||p||^2.
__global__ void prep_kernel(const float* __restrict__ gts, const float* __restrict__ preds,
                            int nG, int nP, unsigned char* __restrict__ recB) {
    const int idx = blockIdx.x * blockDim.x + threadIdx.x;
    if (idx >= nG + nP) return;
    const float* src;
    unsigned char* rb;
    if (idx < nG) {
        src = gts + 3 * (size_t)idx;
        rb  = recB + (size_t)(idx >> 5) * 1024 + (size_t)(idx & 31) * 16;
    } else {
        const int j = idx - nG;
        src = preds + 3 * (size_t)j;
        rb  = recB + (size_t)nG * 32 + (size_t)(j >> 5) * 1024 + (size_t)(j & 31) * 16;
    }
    const float x = src[0], y = src[1], z = src[2];
    const float w = -0.5f * (x * x + y * y + z * z);
    unsigned int xh, xl, yh, yl, zh, zl, wh, wl;
    cvt_split(x, xh, xl); cvt_split(y, yh, yl);
    cvt_split(z, zh, zl); cvt_split(w, wh, wl);
    const unsigned int hx = xh | (yh << 16), hz = zh | (wh << 16);
    const unsigned int lx = xl | (yl << 16), lz = zl | (wl << 16);
    *(uint4*)(rb)       = make_uint4(hx, hz, hx, hz);
    *(uint4*)(rb + 512) = make_uint4(lx, lz, 0u, 0u);
}

__global__ void __launch_bounds__(BLOCK, 4)
chamfer_kernel(const float* __restrict__ gts, const float* __restrict__ preds,
               const uint4* __restrict__ recB, int N, int M, int B,
               float invx, float invy, float* __restrict__ out) {
    const int z = blockIdx.y;
    const bool dirX = (z < B);
    const int b = dirX ? z : z - B;
    const int NQ = dirX ? N : M;
    const int NR = dirX ? M : N;
    const float* Q = (dirX ? gts : preds) + (size_t)b * NQ * 3;
    const float inv = dirX ? invx : invy;
    const uint4* Rb4 = recB + (dirX ? (size_t)B * N * 2 : 0) + (size_t)b * NR * 2;

    const int tid = threadIdx.x;
    const int lane = tid & 63;
    const int wave = tid >> 6;
    const int m = lane & 31;
    const bool isHi = lane < 32;
    const unsigned int loMask = isHi ? 0xFFFFFFFFu : 0u;
    const int qBase = (blockIdx.x * WAVES + wave) * QPW;

    // ---- A fragment from raw queries (once; negligible). Exact fp32 norm.
    float n2q;
    short8 A0;
    {
        const float* qp = Q + 3 * (size_t)(qBase + m);
        const float x = qp[0], y = qp[1], zz = qp[2];
        n2q = x * x + y * y + zz * zz;
        unsigned int xh, xl, yh, yl, zh, zl;
        cvt_split(x, xh, xl); cvt_split(y, yh, yl); cvt_split(zz, zh, zl);
        uint4 a = make_uint4(xh | (yh << 16), zh | 0x3F800000u,
                             (xl | (yl << 16)) & loMask, zl & loMask);
        A0 = __builtin_bit_cast(short8, a);
    }

    f32x16 k0, zc;
    #pragma unroll
    for (int r = 0; r < 16; ++r) { k0[r] = -INFINITY; zc[r] = 0.0f; }

    // Lane l reads its 16B fragment of tile t at Rb4[t*64 + lane].
    // S/T ping-pong, 2 tiles per set, distance = 2 compute blocks.
    // Fold: fmaxf(fmaxf(c0,c1),k) -> LLVM fuses to v_max3_f32 (compiler-
    // known path, hazard recognizer active end-to-end).
#define DO2(ba, bb) do {                                                     \
        const short8 sa_ = __builtin_bit_cast(short8, (ba));                 \
        const short8 sb_ = __builtin_bit_cast(short8, (bb));                 \
        const f32x16 c0_ = MFMA(A0, sa_, zc);                                \
        const f32x16 c1_ = MFMA(A0, sb_, zc);                                \
        _Pragma("unroll")                                                    \
        for (int r = 0; r < 16; ++r)                                         \
            k0[r] = fmaxf(fmaxf(c0_[r], c1_[r]), k0[r]);                     \
    } while (0)

    const int NT = NR / 32;                         // 256 tiles
    const uint4* p = Rb4 + lane;
    uint4 S0 = p[0], S1 = p[64];
    uint4 T0 = p[128], T1 = p[192];
    #pragma unroll 1
    for (int t = 0; t < NT; t += 4) {
        // consume S (tiles t,t+1); prefetch tiles t+4,t+5
        const uint4 nS0 = p[256], nS1 = p[320];
        DO2(S0, S1);
        // consume T (tiles t+2,t+3); prefetch tiles t+6,t+7
        const uint4 nT0 = p[384], nT1 = p[448];     // last iter: 4KB over-read
        DO2(T0, T1);                                // into ws interior, unused
        S0 = nS0; S1 = nS1; T0 = nT0; T1 = nT1;
        p += 256;
    }
#undef DO2

    // ---- epilogue: wave-private LDS transpose, then row max-reduce.
    // C/D layout: col=lane&31, row=(r&3)+8*(r>>2)+4*(lane>>5).
    __shared__ float sT[WAVES][32][36];             // +4 pad; 18 KB total
    #pragma unroll
    for (int r = 0; r < 16; ++r) {
        const int row = (r & 3) + 8 * (r >> 2) + 4 * (lane >> 5);
        sT[wave][row][m] = k0[r];
    }
    // lane l reduces half of row (l&31): cols (l>>5)*16 .. +15
    const float4* rowp = (const float4*)&sT[wave][lane & 31][(lane >> 5) * 16];
    float4 m01 = rowp[0];
    #pragma unroll
    for (int kk = 1; kk < 4; ++kk) {
        const float4 t = rowp[kk];
        m01.x = fmaxf(m01.x, t.x); m01.y = fmaxf(m01.y, t.y);
        m01.z = fmaxf(m01.z, t.z); m01.w = fmaxf(m01.w, t.w);
    }
    float rmax = fmaxf(fmaxf(m01.x, m01.y), fmaxf(m01.z, m01.w));
    rmax = fmaxf(rmax, __shfl_xor(rmax, 32));       // combine col halves

    // query qBase+m owned by the lane<32 copy; exact fp32 norm from prologue
    float v = isHi ? fmaxf(n2q - 2.0f * rmax, 0.0f) * inv : 0.0f;

    // block reduction -> one atomicAdd (out zeroed by harness each iter)
    #pragma unroll
    for (int off = 32; off; off >>= 1) v += __shfl_xor(v, off);
    __shared__ float waveSums[WAVES];
    if (lane == 0) waveSums[wave] = v;
    __syncthreads();
    if (tid == 0) {
        float s = 0.0f;
        #pragma unroll
        for (int w = 0; w < WAVES; ++w) s += waveSums[w];
        atomicAdd(out, s);
    }
}

extern "C" void kernel_launch(void* const* d_in, const int* in_sizes, int n_in,
                              void* d_out, int out_size, void* d_ws, size_t ws_size,
                              hipStream_t stream) {
    const float* gts   = (const float*)d_in[0];   // [B, N, 3]
    const float* preds = (const float*)d_in[1];   // [B, M, 3]
    float* out = (float*)d_out;

    const int B = 8;
    const int N = in_sizes[0] / (B * 3);
    const int M = in_sizes[1] / (B * 3);
    const int nG = B * N, nP = B * M;

    unsigned char* recB = (unsigned char*)d_ws;   // (nG+nP)*32B = 4 MB

    prep_kernel<<<(nG + nP + BLOCK - 1) / BLOCK, BLOCK, 0, stream>>>(
        gts, preds, nG, nP, recB);

    dim3 grid(N / (WAVES * QPW), 2 * B);          // 64 x 16 = 1024 = 4/CU
    chamfer_kernel<<<grid, BLOCK, 0, stream>>>(
        gts, preds, (const uint4*)recB, N, M, B,
        1.0f / (float)nG, 1.0f / (float)nP, out);
}

// Round 11
// 100.670 us; speedup vs baseline: 1.0477x; 1.0477x over previous
//
#include <hip/hip_runtime.h>
#include <hip/hip_bf16.h>
#include <math.h>

// Chamfer distance, B=8, N=M=8192, D=3, fp32.
//   C[m][n] = q_m.r_n - 0.5*||r_n||^2 via ONE v_mfma_f32_32x32x16_bf16:
//     lanes<32  (k0-7) : A={qh,1, ql,0}  B={rh,wh, rh,wh}
//     lanes>=32 (k8-15): A={qh,1, 0,0}   B={rl,wl, 0,0}
//   min_j d2 = ||q||^2_fp32 - 2*max_n C, clamped at 0.
// R17: R16 proved occupancy is NOT the lever (2x occupancy -> slower).
// Both R14/R16: MFMA busy 33k cyc/CU + VALU 39k + stall residue 32-49k.
// With VGPR_Count=40 the compiler kept only ~1 c-tuple live -> every fold
// sat in its producer MFMA's latency shadow (~256 exposures/wave) = the
// residue. Fix on the CLEAN INTRINSIC path (R10 tried this with asm and was
// poisoned by accvgpr junk):
//   - 2-deep fold lag: ping-pong cA/cB tuple sets; body issues group a+1
//     while folding group a. All compiler-known instrs (hazards modeled,
//     fold reorder is max-commutative -> bit-identical).
//   - self-overwriting X0..X7 tile buffer: each pair reloaded right after
//     last use (load->use >= 3/4 body ~700cyc) -> NO S/T copy movs.
//   - QPW=64, 512 blocks = 2/CU (R14's better geometry, half the L2
//     traffic of R16), launch_bounds(256,2), ~212 regs.
//   - last body's dangling MFMA group reads the documented +8KB over-read
//     (ws interior) and is never folded.
// Predicted: chamfer 50.3 -> 18-26us (MfmaUtil 55-75), total ~68-76us.
// Pre-commit: chamfer >=35us with both pipes <40% => ~42us is this
// algorithm's attractor; declare at best-achieved.

#define BLOCK 256
#define WAVES 4
#define QPW 64        // queries per wave (two 32-row MFMA groups)

typedef short short8 __attribute__((ext_vector_type(8)));
typedef float f32x16 __attribute__((ext_vector_type(16)));

__device__ __forceinline__ unsigned int bf16hi(float f) {
    __hip_bfloat16 h = __float2bfloat16(f);
    return (unsigned int)*reinterpret_cast<unsigned short*>(&h);
}
__device__ __forceinline__ float bf16f(unsigned int u) {
    unsigned int v = u << 16;
    return *reinterpret_cast<float*>(&v);
}
__device__ __forceinline__ void cvt_split(float v, unsigned int& hi, unsigned int& lo) {
    hi = bf16hi(v);
    lo = bf16hi(v - bf16f(hi));
}

#define MFMA(a, b, c) __builtin_amdgcn_mfma_f32_32x32x16_bf16((a), (b), (c), 0, 0, 0)
#define BC8(x) __builtin_bit_cast(short8, (x))

// recB: pre-expanded B-fragment stream, tile t = points [32t,32t+32),
// 1024B per tile:
//   bytes [t*1024 + m*16]       = {hx,hz, hx,hz}  (hi dup, consumed by lanes<32)
//   bytes [t*1024 + 512 + m*16] = {lx,lz, 0, 0}   (lo,     consumed by lanes>=32)
// where hx = xh|(yh<<16), hz = zh|(wh<<16), w = -0.5*||p||^2.
__global__ void prep_kernel(const float* __restrict__ gts, const float* __restrict__ preds,
                            int nG, int nP, unsigned char* __restrict__ recB) {
    const int idx = blockIdx.x * blockDim.x + threadIdx.x;
    if (idx >= nG + nP) return;
    const float* src;
    unsigned char* rb;
    if (idx < nG) {
        src = gts + 3 * (size_t)idx;
        rb  = recB + (size_t)(idx >> 5) * 1024 + (size_t)(idx & 31) * 16;
    } else {
        const int j = idx - nG;
        src = preds + 3 * (size_t)j;
        rb  = recB + (size_t)nG * 32 + (size_t)(j >> 5) * 1024 + (size_t)(j & 31) * 16;
    }
    const float x = src[0], y = src[1], z = src[2];
    const float w = -0.5f * (x * x + y * y + z * z);
    unsigned int xh, xl, yh, yl, zh, zl, wh, wl;
    cvt_split(x, xh, xl); cvt_split(y, yh, yl);
    cvt_split(z, zh, zl); cvt_split(w, wh, wl);
    const unsigned int hx = xh | (yh << 16), hz = zh | (wh << 16);
    const unsigned int lx = xl | (yl << 16), lz = zl | (wl << 16);
    *(uint4*)(rb)       = make_uint4(hx, hz, hx, hz);
    *(uint4*)(rb + 512) = make_uint4(lx, lz, 0u, 0u);
}

__global__ void __launch_bounds__(BLOCK, 2)
chamfer_kernel(const float* __restrict__ gts, const float* __restrict__ preds,
               const uint4* __restrict__ recB, int N, int M, int B,
               float invx, float invy, float* __restrict__ out) {
    const int z = blockIdx.y;
    const bool dirX = (z < B);
    const int b = dirX ? z : z - B;
    const int NQ = dirX ? N : M;
    const int NR = dirX ? M : N;
    const float* Q = (dirX ? gts : preds) + (size_t)b * NQ * 3;
    const float inv = dirX ? invx : invy;
    const uint4* Rb4 = recB + (dirX ? (size_t)B * N * 2 : 0) + (size_t)b * NR * 2;

    const int tid = threadIdx.x;
    const int lane = tid & 63;
    const int wave = tid >> 6;
    const int m = lane & 31;
    const bool isHi = lane < 32;
    const unsigned int loMask = isHi ? 0xFFFFFFFFu : 0u;
    const int qBase = (blockIdx.x * WAVES + wave) * QPW;

    // ---- A fragments from raw queries (once; negligible). Exact fp32 norms.
    float n2q0, n2q1;
    short8 A0, A1;
    {
        const float* qp = Q + 3 * (size_t)(qBase + m);
        const float x = qp[0], y = qp[1], zz = qp[2];
        n2q0 = x * x + y * y + zz * zz;
        unsigned int xh, xl, yh, yl, zh, zl;
        cvt_split(x, xh, xl); cvt_split(y, yh, yl); cvt_split(zz, zh, zl);
        uint4 a = make_uint4(xh | (yh << 16), zh | 0x3F800000u,
                             (xl | (yl << 16)) & loMask, zl & loMask);
        A0 = BC8(a);
    }
    {
        const float* qp = Q + 3 * (size_t)(qBase + 32 + m);
        const float x = qp[0], y = qp[1], zz = qp[2];
        n2q1 = x * x + y * y + zz * zz;
        unsigned int xh, xl, yh, yl, zh, zl;
        cvt_split(x, xh, xl); cvt_split(y, yh, yl); cvt_split(zz, zh, zl);
        uint4 a = make_uint4(xh | (yh << 16), zh | 0x3F800000u,
                             (xl | (yl << 16)) & loMask, zl & loMask);
        A1 = BC8(a);
    }

    f32x16 k0, k1, zc;
    #pragma unroll
    for (int r = 0; r < 16; ++r) { k0[r] = -INFINITY; k1[r] = -INFINITY; zc[r] = 0.0f; }

    // 2-deep ping-pong MFMA tuple sets.
    f32x16 cA0, cA1, cA2, cA3, cB0, cB1, cB2, cB3;

    // Issue one group (2 ref tiles ba,bb x A0,A1 = 4 MFMA) into set P.
#define MF4(P, ba, bb) do {                                                  \
        P##0 = MFMA(A0, BC8(ba), zc);                                        \
        P##1 = MFMA(A0, BC8(bb), zc);                                        \
        P##2 = MFMA(A1, BC8(ba), zc);                                        \
        P##3 = MFMA(A1, BC8(bb), zc);                                        \
    } while (0)
    // Fold set P into running maxima (32 v_max3 via maxnum fusion).
#define FOLD(P) do {                                                         \
        _Pragma("unroll")                                                    \
        for (int r = 0; r < 16; ++r)                                         \
            k0[r] = fmaxf(fmaxf(P##0[r], P##1[r]), k0[r]);                   \
        _Pragma("unroll")                                                    \
        for (int r = 0; r < 16; ++r)                                         \
            k1[r] = fmaxf(fmaxf(P##2[r], P##3[r]), k1[r]);                   \
    } while (0)

    // Lane l reads its 16B fragment of tile t at Rb4[t*64 + lane].
    // Body = 8 tiles (4 groups). Self-overwriting buffer X0..X7: each pair
    // reloaded with next body's tiles right after its last use.
    const int NT = NR / 32;                         // 256 tiles, 32 bodies
    const uint4* p = Rb4 + lane;
    uint4 X0 = p[0],   X1 = p[64],  X2 = p[128], X3 = p[192];
    uint4 X4 = p[256], X5 = p[320], X6 = p[384], X7 = p[448];
    MF4(cA, X0, X1);                                // group 0 in flight

    #pragma unroll 1
    for (int bdy = 0; bdy < NT / 8; ++bdy) {
        // entry invariant: cA = group a (= first group of this body), issued
        X0 = p[512]; X1 = p[576];                   // next body's tiles 0,1
        MF4(cB, X2, X3);  FOLD(cA);                 // issue a+1, fold a
        X2 = p[640]; X3 = p[704];
        MF4(cA, X4, X5);  FOLD(cB);                 // issue a+2, fold a+1
        X4 = p[768]; X5 = p[832];
        MF4(cB, X6, X7);  FOLD(cA);                 // issue a+3, fold a+2
        X6 = p[896]; X7 = p[960];
        MF4(cA, X0, X1);  FOLD(cB);                 // issue a+4 (next body's
        p += 512;                                   //  first), fold a+3
    }
    // Last body issued a garbage group (tiles NT..NT+1, from the ~8KB
    // over-read past this direction's chunk - still inside recB/ws, never
    // folded; NaNs cannot propagate).
#undef MF4
#undef FOLD

    // ---- epilogue: wave-private LDS transpose, then row max-reduce.
    // C/D layout: col=lane&31, row=(r&3)+8*(r>>2)+4*(lane>>5).
    __shared__ float sT[WAVES][64][36];             // +4 pad: conflict-free
    #pragma unroll
    for (int r = 0; r < 16; ++r) {
        const int row = (r & 3) + 8 * (r >> 2) + 4 * (lane >> 5);
        sT[wave][row][m]      = k0[r];              // group 0 -> rows 0..31
        sT[wave][32 + row][m] = k1[r];              // group 1 -> rows 32..63
    }
    const float4* rowp = (const float4*)&sT[wave][lane][0];
    float4 m01 = rowp[0];
    #pragma unroll
    for (int kk = 1; kk < 8; ++kk) {
        const float4 t = rowp[kk];
        m01.x = fmaxf(m01.x, t.x); m01.y = fmaxf(m01.y, t.y);
        m01.z = fmaxf(m01.z, t.z); m01.w = fmaxf(m01.w, t.w);
    }
    const float cmax = fmaxf(fmaxf(m01.x, m01.y), fmaxf(m01.z, m01.w));

    // lane owns query qBase+lane; exact fp32 norm from the prologue.
    const float q2own = isHi ? n2q0 : n2q1;
    float v = fmaxf(q2own - 2.0f * cmax, 0.0f) * inv;

    // block reduction -> one atomicAdd (out zeroed by harness each iter)
    #pragma unroll
    for (int off = 32; off; off >>= 1) v += __shfl_xor(v, off);
    __shared__ float waveSums[WAVES];
    if (lane == 0) waveSums[wave] = v;
    __syncthreads();
    if (tid == 0) {
        float s = 0.0f;
        #pragma unroll
        for (int w = 0; w < WAVES; ++w) s += waveSums[w];
        atomicAdd(out, s);
    }
}

extern "C" void kernel_launch(void* const* d_in, const int* in_sizes, int n_in,
                              void* d_out, int out_size, void* d_ws, size_t ws_size,
                              hipStream_t stream) {
    const float* gts   = (const float*)d_in[0];   // [B, N, 3]
    const float* preds = (const float*)d_in[1];   // [B, M, 3]
    float* out = (float*)d_out;

    const int B = 8;
    const int N = in_sizes[0] / (B * 3);
    const int M = in_sizes[1] / (B * 3);
    const int nG = B * N, nP = B * M;

    unsigned char* recB = (unsigned char*)d_ws;   // (nG+nP)*32B = 4MB (+8KB
                                                  //  over-read slack in ws)
    prep_kernel<<<(nG + nP + BLOCK - 1) / BLOCK, BLOCK, 0, stream>>>(
        gts, preds, nG, nP, recB);

    dim3 grid(N / (WAVES * QPW), 2 * B);          // 32 x 16 = 512 = 2/CU
    chamfer_kernel<<<grid, BLOCK, 0, stream>>>(
        gts, preds, (const uint4*)recB, N, M, B,
        1.0f / (float)nG, 1.0f / (float)nP, out);
}

// Round 12
// 94.847 us; speedup vs baseline: 1.1120x; 1.0614x over previous
//
#include <hip/hip_runtime.h>
#include <hip/hip_bf16.h>
#include <math.h>

// Chamfer distance, B=8, N=M=8192, D=3, fp32.
//   C[m][n] = q_m.r_n - 0.5*||r_n||^2 via ONE v_mfma_f32_32x32x16_bf16:
//     lanes<32  (k0-7) : A={qh,1, ql,0}  B={rh,wh, rh,wh}
//     lanes>=32 (k8-15): A={qh,1, 0,0}   B={rl,wl, 0,0}
//   min_j d2 = ||q||^2_fp32 - 2*max_n C, clamped at 0.
// R18: R17's VGPR_Count=68 PROVED the MachineScheduler collapsed the 2-deep
// pipeline (needs >=190 regs) back to issue->fold order - R17 never tested
// the hypothesis. The ~40% stall residue = hazard-recognizer MFMA->VALU-read
// padding (~24cyc) x 128 groups/wave, unhidden at 2 waves/SIMD. This round:
// SAME pipeline, pinned with sched_barrier(0) around each phase so the
// scheduler cannot re-fuse producer and consumer:
//   phase A: {2 loads; 4 MFMA intrinsic -> set P} | SB
//   phase B: {32 max3 folding the OTHER set}      | SB
// Fold-to-producer distance >= 1 full group (>=128cyc) -> zero hazard nops.
// All compiler-known instructions (hazard recognizer active end-to-end ->
// numerically safe; fold reorder is max-commutative). ~230 regs, lb(256,2).
// Smoking gun: VGPR_Count must jump to >=190. Predicted: chamfer 46.8 ->
// 18-26us (MfmaUtil 55-75), total ~70-78us.
// FINAL pre-commit: if chamfer >=35us WITH the pipeline held (VGPR>=190),
// the ~900cyc/group period is HW-structural; declare roofline-at-best next.

#define BLOCK 256
#define WAVES 4
#define QPW 64        // queries per wave (two 32-row MFMA groups)

typedef short short8 __attribute__((ext_vector_type(8)));
typedef float f32x16 __attribute__((ext_vector_type(16)));

__device__ __forceinline__ unsigned int bf16hi(float f) {
    __hip_bfloat16 h = __float2bfloat16(f);
    return (unsigned int)*reinterpret_cast<unsigned short*>(&h);
}
__device__ __forceinline__ float bf16f(unsigned int u) {
    unsigned int v = u << 16;
    return *reinterpret_cast<float*>(&v);
}
__device__ __forceinline__ void cvt_split(float v, unsigned int& hi, unsigned int& lo) {
    hi = bf16hi(v);
    lo = bf16hi(v - bf16f(hi));
}

#define MFMA(a, b, c) __builtin_amdgcn_mfma_f32_32x32x16_bf16((a), (b), (c), 0, 0, 0)
#define BC8(x) __builtin_bit_cast(short8, (x))
#define SB()  __builtin_amdgcn_sched_barrier(0)

// recB: pre-expanded B-fragment stream, tile t = points [32t,32t+32),
// 1024B per tile:
//   bytes [t*1024 + m*16]       = {hx,hz, hx,hz}  (hi dup, consumed by lanes<32)
//   bytes [t*1024 + 512 + m*16] = {lx,lz, 0, 0}   (lo,     consumed by lanes>=32)
// where hx = xh|(yh<<16), hz = zh|(wh<<16), w = -0.5*||p||^2.
__global__ void prep_kernel(const float* __restrict__ gts, const float* __restrict__ preds,
                            int nG, int nP, unsigned char* __restrict__ recB) {
    const int idx = blockIdx.x * blockDim.x + threadIdx.x;
    if (idx >= nG + nP) return;
    const float* src;
    unsigned char* rb;
    if (idx < nG) {
        src = gts + 3 * (size_t)idx;
        rb  = recB + (size_t)(idx >> 5) * 1024 + (size_t)(idx & 31) * 16;
    } else {
        const int j = idx - nG;
        src = preds + 3 * (size_t)j;
        rb  = recB + (size_t)nG * 32 + (size_t)(j >> 5) * 1024 + (size_t)(j & 31) * 16;
    }
    const float x = src[0], y = src[1], z = src[2];
    const float w = -0.5f * (x * x + y * y + z * z);
    unsigned int xh, xl, yh, yl, zh, zl, wh, wl;
    cvt_split(x, xh, xl); cvt_split(y, yh, yl);
    cvt_split(z, zh, zl); cvt_split(w, wh, wl);
    const unsigned int hx = xh | (yh << 16), hz = zh | (wh << 16);
    const unsigned int lx = xl | (yl << 16), lz = zl | (wl << 16);
    *(uint4*)(rb)       = make_uint4(hx, hz, hx, hz);
    *(uint4*)(rb + 512) = make_uint4(lx, lz, 0u, 0u);
}

__global__ void __launch_bounds__(BLOCK, 2)
chamfer_kernel(const float* __restrict__ gts, const float* __restrict__ preds,
               const uint4* __restrict__ recB, int N, int M, int B,
               float invx, float invy, float* __restrict__ out) {
    const int z = blockIdx.y;
    const bool dirX = (z < B);
    const int b = dirX ? z : z - B;
    const int NQ = dirX ? N : M;
    const int NR = dirX ? M : N;
    const float* Q = (dirX ? gts : preds) + (size_t)b * NQ * 3;
    const float inv = dirX ? invx : invy;
    const uint4* Rb4 = recB + (dirX ? (size_t)B * N * 2 : 0) + (size_t)b * NR * 2;

    const int tid = threadIdx.x;
    const int lane = tid & 63;
    const int wave = tid >> 6;
    const int m = lane & 31;
    const bool isHi = lane < 32;
    const unsigned int loMask = isHi ? 0xFFFFFFFFu : 0u;
    const int qBase = (blockIdx.x * WAVES + wave) * QPW;

    // ---- A fragments from raw queries (once; negligible). Exact fp32 norms.
    float n2q0, n2q1;
    short8 A0, A1;
    {
        const float* qp = Q + 3 * (size_t)(qBase + m);
        const float x = qp[0], y = qp[1], zz = qp[2];
        n2q0 = x * x + y * y + zz * zz;
        unsigned int xh, xl, yh, yl, zh, zl;
        cvt_split(x, xh, xl); cvt_split(y, yh, yl); cvt_split(zz, zh, zl);
        uint4 a = make_uint4(xh | (yh << 16), zh | 0x3F800000u,
                             (xl | (yl << 16)) & loMask, zl & loMask);
        A0 = BC8(a);
    }
    {
        const float* qp = Q + 3 * (size_t)(qBase + 32 + m);
        const float x = qp[0], y = qp[1], zz = qp[2];
        n2q1 = x * x + y * y + zz * zz;
        unsigned int xh, xl, yh, yl, zh, zl;
        cvt_split(x, xh, xl); cvt_split(y, yh, yl); cvt_split(zz, zh, zl);
        uint4 a = make_uint4(xh | (yh << 16), zh | 0x3F800000u,
                             (xl | (yl << 16)) & loMask, zl & loMask);
        A1 = BC8(a);
    }

    f32x16 k0, k1, zc;
    #pragma unroll
    for (int r = 0; r < 16; ++r) { k0[r] = -INFINITY; k1[r] = -INFINITY; zc[r] = 0.0f; }

    // 2-deep ping-pong MFMA tuple sets (pinned live by the SB fences).
    f32x16 cA0, cA1, cA2, cA3, cB0, cB1, cB2, cB3;

    // Issue one group (2 ref tiles ba,bb x A0,A1 = 4 MFMA) into set P.
#define MF4(P, ba, bb) do {                                                  \
        P##0 = MFMA(A0, BC8(ba), zc);                                        \
        P##1 = MFMA(A0, BC8(bb), zc);                                        \
        P##2 = MFMA(A1, BC8(ba), zc);                                        \
        P##3 = MFMA(A1, BC8(bb), zc);                                        \
    } while (0)
    // Fold set P into running maxima (32 v_max3 via maxnum fusion).
#define FOLD(P) do {                                                         \
        _Pragma("unroll")                                                    \
        for (int r = 0; r < 16; ++r)                                         \
            k0[r] = fmaxf(fmaxf(P##0[r], P##1[r]), k0[r]);                   \
        _Pragma("unroll")                                                    \
        for (int r = 0; r < 16; ++r)                                         \
            k1[r] = fmaxf(fmaxf(P##2[r], P##3[r]), k1[r]);                   \
    } while (0)

    // Lane l reads its 16B fragment of tile t at Rb4[t*64 + lane].
    // Body = 8 tiles (4 groups). Self-overwriting buffer X0..X7: each pair
    // reloaded with next body's tiles right after its last use.
    const int NT = NR / 32;                         // 256 tiles, 32 bodies
    const uint4* p = Rb4 + lane;
    uint4 X0 = p[0],   X1 = p[64],  X2 = p[128], X3 = p[192];
    uint4 X4 = p[256], X5 = p[320], X6 = p[384], X7 = p[448];
    MF4(cA, X0, X1);                                // group 0 in flight
    SB();

    #pragma unroll 1
    for (int bdy = 0; bdy < NT / 8; ++bdy) {
        // entry invariant: cA = group a (first group of this body), issued
        X0 = p[512]; X1 = p[576];                   // next body's tiles 0,1
        MF4(cB, X2, X3);
        SB();                                       // pin: fold can't move up
        FOLD(cA);                                   // reads group issued LAST
        SB();                                       //  phase (>=128cyc old)
        X2 = p[640]; X3 = p[704];
        MF4(cA, X4, X5);
        SB();
        FOLD(cB);
        SB();
        X4 = p[768]; X5 = p[832];
        MF4(cB, X6, X7);
        SB();
        FOLD(cA);
        SB();
        X6 = p[896]; X7 = p[960];
        MF4(cA, X0, X1);                            // next body's first group
        SB();
        FOLD(cB);
        SB();
        p += 512;
    }
    // Last body issued a garbage group (tiles NT..NT+1 from the ~8KB
    // over-read past this direction's chunk - still inside recB/ws, never
    // folded; NaNs cannot propagate).
#undef MF4
#undef FOLD

    // ---- epilogue: wave-private LDS transpose, then row max-reduce.
    // C/D layout: col=lane&31, row=(r&3)+8*(r>>2)+4*(lane>>5).
    __shared__ float sT[WAVES][64][36];             // +4 pad: conflict-free
    #pragma unroll
    for (int r = 0; r < 16; ++r) {
        const int row = (r & 3) + 8 * (r >> 2) + 4 * (lane >> 5);
        sT[wave][row][m]      = k0[r];              // group 0 -> rows 0..31
        sT[wave][32 + row][m] = k1[r];              // group 1 -> rows 32..63
    }
    const float4* rowp = (const float4*)&sT[wave][lane][0];
    float4 m01 = rowp[0];
    #pragma unroll
    for (int kk = 1; kk < 8; ++kk) {
        const float4 t = rowp[kk];
        m01.x = fmaxf(m01.x, t.x); m01.y = fmaxf(m01.y, t.y);
        m01.z = fmaxf(m01.z, t.z); m01.w = fmaxf(m01.w, t.w);
    }
    const float cmax = fmaxf(fmaxf(m01.x, m01.y), fmaxf(m01.z, m01.w));

    // lane owns query qBase+lane; exact fp32 norm from the prologue.
    const float q2own = isHi ? n2q0 : n2q1;
    float v = fmaxf(q2own - 2.0f * cmax, 0.0f) * inv;

    // block reduction -> one atomicAdd (out zeroed by harness each iter)
    #pragma unroll
    for (int off = 32; off; off >>= 1) v += __shfl_xor(v, off);
    __shared__ float waveSums[WAVES];
    if (lane == 0) waveSums[wave] = v;
    __syncthreads();
    if (tid == 0) {
        float s = 0.0f;
        #pragma unroll
        for (int w = 0; w < WAVES; ++w) s += waveSums[w];
        atomicAdd(out, s);
    }
}

extern "C" void kernel_launch(void* const* d_in, const int* in_sizes, int n_in,
                              void* d_out, int out_size, void* d_ws, size_t ws_size,
                              hipStream_t stream) {
    const float* gts   = (const float*)d_in[0];   // [B, N, 3]
    const float* preds = (const float*)d_in[1];   // [B, M, 3]
    float* out = (float*)d_out;

    const int B = 8;
    const int N = in_sizes[0] / (B * 3);
    const int M = in_sizes[1] / (B * 3);
    const int nG = B * N, nP = B * M;

    unsigned char* recB = (unsigned char*)d_ws;   // (nG+nP)*32B = 4MB (+8KB
                                                  //  over-read slack in ws)
    prep_kernel<<<(nG + nP + BLOCK - 1) / BLOCK, BLOCK, 0, stream>>>(
        gts, preds, nG, nP, recB);

    dim3 grid(N / (WAVES * QPW), 2 * B);          // 32 x 16 = 512 = 2/CU
    chamfer_kernel<<<grid, BLOCK, 0, stream>>>(
        gts, preds, (const uint4*)recB, N, M, B,
        1.0f / (float)nG, 1.0f / (float)nP, out);
}